// Round 9
// baseline (858.351 us; speedup 1.0000x reference)
//
#include <hip/hip_runtime.h>
#include <stdint.h>

#define D 128
#define E_EDGES 600000
#define E2 1200000
#define N_USER_C 100000
#define N_ITEM_C 50000
#define NSEG_TOT 150000
#define NCPAD 150528          // 147*1024 scan padding
#define NSCAN_BLOCKS 147
#define NEG_SLOPE 0.01f
#define LN_EPS 1e-5f

#define CONV_BLOCKS 1280      // fused conv grid
#define ITEM_BLOCKS 480       // 3:5 split ~ chunk+epilogue work ratio
#define HIST_BLOCKS ((E2 + 255) / 256)
#define CVT_BLOCKS 1024

typedef __attribute__((ext_vector_type(8))) _Float16 f16x8;
typedef __attribute__((ext_vector_type(4))) float f32x4;
typedef __attribute__((ext_vector_type(2))) float f32x2;

// ---------------- prep: histogram + fp32->fp16 convert + flag init ----------------
__global__ void prep_k(const int* __restrict__ edst_ui, const int* __restrict__ edst_iu,
                       int* __restrict__ counts, int* __restrict__ totals,
                       const float* __restrict__ xu, const float* __restrict__ xi,
                       _Float16* __restrict__ xuh, _Float16* __restrict__ xih,
                       _Float16* __restrict__ zrow) {
    const int b = blockIdx.x;
    if (b < HIST_BLOCKS) {
        int e = b * 256 + threadIdx.x;
        if (e < E_EDGES)      atomicAdd(&counts[edst_ui[e]], 1);
        else if (e < E2)      atomicAdd(&counts[N_ITEM_C + edst_iu[e - E_EDGES]], 1);
    } else {
        int tid = (b - HIST_BLOCKS) * 256 + threadIdx.x;
        if (b == HIST_BLOCKS) {
            if (threadIdx.x < 160) totals[threadIdx.x] = -1;   // lookback sentinels
            if (threadIdx.x < 32) ((uint2*)zrow)[threadIdx.x] = (uint2){0u, 0u};
        }
        const int NU4 = N_USER_C * 32;        // float4 count, user block
        const int NT4 = NU4 + N_ITEM_C * 32;
        for (int v = tid; v < NT4; v += CVT_BLOCKS * 256) {
            const bool isu = v < NU4;
            const float4 f = isu ? ((const float4*)xu)[v] : ((const float4*)xi)[v - NU4];
            _Float16* o = isu ? (xuh + (size_t)v * 4) : (xih + (size_t)(v - NU4) * 4);
            uint2 p;
            p.x = __builtin_bit_cast(uint32_t, __builtin_amdgcn_cvt_pkrtz(f.x, f.y));
            p.y = __builtin_bit_cast(uint32_t, __builtin_amdgcn_cvt_pkrtz(f.z, f.w));
            *(uint2*)o = p;
        }
    }
}

// ---------------- single-pass exclusive scan (decoupled lookback) ----------------
__global__ void scan_full_k(int* __restrict__ counts, int* __restrict__ offsets,
                            int* __restrict__ totals) {
    __shared__ int sm[1024];
    __shared__ int psum;
    const int t = threadIdx.x;
    const int b = blockIdx.x;
    const int i = b * 1024 + t;
    const int v = counts[i];
    sm[t] = v;
    __syncthreads();
    for (int off = 1; off < 1024; off <<= 1) {
        int x = (t >= off) ? sm[t - off] : 0;
        __syncthreads();
        sm[t] += x;
        __syncthreads();
    }
    const int incl = sm[t];
    if (t == 1023)
        __hip_atomic_store(&totals[b], incl, __ATOMIC_RELEASE, __HIP_MEMORY_SCOPE_AGENT);
    if (t == 0) psum = 0;
    __syncthreads();
    if (t < b) {
        int x;
        do {
            x = __hip_atomic_load(&totals[t], __ATOMIC_ACQUIRE, __HIP_MEMORY_SCOPE_AGENT);
        } while (x < 0);
        atomicAdd(&psum, x);
    }
    __syncthreads();
    offsets[i] = incl - v + psum;
    counts[i] = 0;                         // cursor for scatter
}

__global__ void scatter_k(const int* __restrict__ esrc_ui, const int* __restrict__ edst_ui,
                          const int* __restrict__ esrc_iu, const int* __restrict__ edst_iu,
                          const int* __restrict__ offsets, int* __restrict__ counts,
                          int* __restrict__ sorted) {
    int e = blockIdx.x * 256 + threadIdx.x;
    int s, c;
    if (e < E_EDGES)      { s = esrc_ui[e];            c = edst_ui[e]; }
    else if (e < E2)      { s = esrc_iu[e - E_EDGES];  c = N_ITEM_C + edst_iu[e - E_EDGES]; }
    else return;
    int pos = offsets[c] + atomicAdd(&counts[c], 1);
    sorted[pos] = s;
}

// ---------------- fused NGCF conv + LayerNorm/ReLU, pipelined ----------------
// Round-8 verified core + depth-1 ROW double-buffer: node B's 8 fp16 row loads
// (4 gather + 4 dst, 32 VGPRs) are issued BEFORE node A's MFMA/epilogue, hiding
// ~500 of the ~600-cycle L2-miss gather latency. Metadata is depth-2 (node C's
// offsets/idx load during node A). All buffers are named A/B sets with explicit
// bottom-of-loop rotation (static indexing; runtime-indexed arrays -> scratch).
// fp16 staging is what makes this fit: rounds 2/3 tried the same pipeline at
// fp32 (64+ staging regs) and spilled; fp16 set = 32 regs, total live ~140/256.
// Extra chunks (deg>16, ~7% of nodes) load inline after chunk-0: their own
// load wait subsumes any drain of B's in-flight loads.
// __launch_bounds__(256,2): (256,3) measured VGPR=84 + 2.5 GB spill FETCH;
// (256,4) catastrophic. Keep 2. WRITE_SIZE is the spill canary (~77 MB clean).
__global__ __launch_bounds__(256, 2) void conv2_k(
    const _Float16* __restrict__ xuh, const _Float16* __restrict__ xih,
    const float* __restrict__ W_ui, const float* __restrict__ b_ui,
    const float* __restrict__ W_iu, const float* __restrict__ b_iu,
    const float* __restrict__ lnw_u, const float* __restrict__ lnb_u,
    const float* __restrict__ lnw_i, const float* __restrict__ lnb_i,
    const int* __restrict__ offsets, const int* __restrict__ sorted,
    const _Float16* __restrict__ zrow,
    float* __restrict__ out_user, float* __restrict__ out_item)
{
    // fragment-major: WtF[(n*4+kt)*64 + lane][0..7] = W[kt*32+(lane>>4)*8+e][n*16+(lane&15)]
    __shared__ _Float16 WtF[32 * 64 * 8];   // 32 KB

    const int rel   = blockIdx.x >= ITEM_BLOCKS;
    const int bid_r = rel ? (blockIdx.x - ITEM_BLOCKS) : blockIdx.x;
    const int nblk  = rel ? (CONV_BLOCKS - ITEM_BLOCKS) : ITEM_BLOCKS;
    const _Float16* __restrict__ xsh = rel ? xih : xuh;
    const _Float16* __restrict__ xdh = rel ? xuh : xih;
    const float* __restrict__ Wp   = rel ? W_iu : W_ui;
    const float* __restrict__ bp   = rel ? b_iu : b_ui;
    const float* __restrict__ lnw  = rel ? lnw_u : lnw_i;
    const float* __restrict__ lnb  = rel ? lnb_u : lnb_i;
    float* __restrict__ outp       = rel ? out_user : out_item;
    const int n_dst = rel ? N_USER_C : N_ITEM_C;
    const int cbase = rel ? N_ITEM_C : 0;

    const int t = threadIdx.x;
    for (int idx = t; idx < 2048; idx += 256) {
        const int frag = idx >> 6, lane = idx & 63;
        const int n = frag >> 2, kt = frag & 3;
        const int col = n * 16 + (lane & 15);
        const int k0  = kt * 32 + (lane >> 4) * 8;
        f16x8 v;
        #pragma unroll
        for (int e = 0; e < 8; e++) v[e] = (_Float16)Wp[(k0 + e) * 128 + col];
        *(f16x8*)&WtF[idx * 8] = v;
    }
    __syncthreads();   // only barrier; WtF read-only afterwards

    const int l    = t & 63;
    const int lo16 = l & 15;
    const int quad = l >> 4;
    const int n0 = 2 * quad, n1 = n0 + 1;
    const int col0 = n0 * 16 + lo16, col1 = n1 * 16 + lo16;

    float bn[8];
    #pragma unroll
    for (int n = 0; n < 8; n++) bn[n] = bp[n * 16 + lo16];
    const float lw0 = lnw[col0], lw1 = lnw[col1];
    const float lb0 = lnb[col0], lb1 = lnb[col1];

    const int stride = nblk * 4;
    int d = bid_r * 4 + (t >> 6);      // first node always exists (waves << n_dst)

    // ---- prologue: meta A, rows A, meta B ----
    int stA  = offsets[cbase + d];
    int lenA = offsets[cbase + d + 1] - stA;
    f16x8 gA[4], rA[4];
    {
        const int idxA = sorted[stA + lo16];        // padded by 16 ints
        const f16x8* pd = (const f16x8*)(xdh + ((size_t)d << 7));
        const bool ok = lo16 < lenA;
        const f16x8* ps = ok ? (const f16x8*)(xsh + ((size_t)idxA << 7))
                             : (const f16x8*)zrow;
        #pragma unroll
        for (int kt = 0; kt < 4; kt++) { rA[kt] = pd[kt * 4 + quad]; gA[kt] = ps[kt * 4 + quad]; }
    }
    int d2 = d + stride;
    bool hasB = d2 < n_dst;
    int stB = 0, enB = 0, idxB = 0;
    if (hasB) { stB = offsets[cbase + d2]; enB = offsets[cbase + d2 + 1]; idxB = sorted[stB + lo16]; }

    while (true) {
        // 1. issue node B's rows (in flight across node A's compute)
        f16x8 gB[4], rB[4];
        const int lenB = enB - stB;
        if (hasB) {
            const f16x8* pd = (const f16x8*)(xdh + ((size_t)d2 << 7));
            const bool ok = lo16 < lenB;
            const f16x8* ps = ok ? (const f16x8*)(xsh + ((size_t)idxB << 7))
                                 : (const f16x8*)zrow;
            #pragma unroll
            for (int kt = 0; kt < 4; kt++) { rB[kt] = pd[kt * 4 + quad]; gB[kt] = ps[kt * 4 + quad]; }
        }
        // 2. meta C (depth-2)
        const int d3 = d2 + stride;
        const bool hasC = hasB && (d3 < n_dst);
        int stC = 0, enC = 0, idxC = 0;
        if (hasC) { stC = offsets[cbase + d3]; enC = offsets[cbase + d3 + 1]; idxC = sorted[stC + lo16]; }

        // 3. compute node A (chunk 0 from prefetched rows; covers len==0 too)
        float nacc[8];
        #pragma unroll
        for (int n = 0; n < 8; n++) nacc[n] = 0.f;

        {
            f16x8 af[4];
            #pragma unroll
            for (int kt = 0; kt < 4; kt++) af[kt] = gA[kt] * rA[kt];   // v_pk_mul_f16
            #pragma unroll
            for (int h = 0; h < 2; h++) {
                f32x4 acc[4];
                #pragma unroll
                for (int n = 0; n < 4; n++) {
                    const float b = bn[h * 4 + n];
                    acc[n] = (f32x4){b, b, b, b};
                }
                #pragma unroll
                for (int kt = 0; kt < 4; kt++) {
                    #pragma unroll
                    for (int n = 0; n < 4; n++) {
                        f16x8 bf = *(const f16x8*)&WtF[(((h * 4 + n) * 4 + kt) * 64 + l) * 8];
                        acc[n] = __builtin_amdgcn_mfma_f32_16x16x32_f16(af[kt], bf, acc[n], 0, 0, 0);
                    }
                }
                #pragma unroll
                for (int n = 0; n < 4; n++) {
                    f32x2 v01 = (f32x2){acc[n][0], acc[n][1]};
                    f32x2 v23 = (f32x2){acc[n][2], acc[n][3]};
                    v01 = __builtin_elementwise_max(v01, v01 * NEG_SLOPE);
                    v23 = __builtin_elementwise_max(v23, v23 * NEG_SLOPE);
                    f32x2 vv = v01 + v23;
                    nacc[h * 4 + n] += vv.x + vv.y;
                }
            }
        }
        // rare extra chunks (deg > 16): inline loads; their wait subsumes gB's
        for (int c0i = 16; c0i < lenA; c0i += 16) {
            const int sj = sorted[stA + c0i + lo16];
            const bool okg = (c0i + lo16) < lenA;
            const f16x8* ps = okg ? (const f16x8*)(xsh + ((size_t)sj << 7))
                                  : (const f16x8*)zrow;
            f16x8 af[4];
            #pragma unroll
            for (int kt = 0; kt < 4; kt++) af[kt] = ps[kt * 4 + quad] * rA[kt];
            #pragma unroll
            for (int h = 0; h < 2; h++) {
                f32x4 acc[4];
                #pragma unroll
                for (int n = 0; n < 4; n++) {
                    const float b = bn[h * 4 + n];
                    acc[n] = (f32x4){b, b, b, b};
                }
                #pragma unroll
                for (int kt = 0; kt < 4; kt++) {
                    #pragma unroll
                    for (int n = 0; n < 4; n++) {
                        f16x8 bf = *(const f16x8*)&WtF[(((h * 4 + n) * 4 + kt) * 64 + l) * 8];
                        acc[n] = __builtin_amdgcn_mfma_f32_16x16x32_f16(af[kt], bf, acc[n], 0, 0, 0);
                    }
                }
                #pragma unroll
                for (int n = 0; n < 4; n++) {
                    f32x2 v01 = (f32x2){acc[n][0], acc[n][1]};
                    f32x2 v23 = (f32x2){acc[n][2], acc[n][3]};
                    v01 = __builtin_elementwise_max(v01, v01 * NEG_SLOPE);
                    v23 = __builtin_elementwise_max(v23, v23 * NEG_SLOPE);
                    f32x2 vv = v01 + v23;
                    nacc[h * 4 + n] += vv.x + vv.y;
                }
            }
        }

        // 4. epilogue: quad-reduce, remove padded-row leaky(bias); LN(node)+ReLU
        const int lim = lenA > 0 ? lenA : 1;
        const int nch = (lim + 15) >> 4;
        const float inv = (float)((nch << 4) - lenA);
        float s1 = 0.f, s2 = 0.f;
        #pragma unroll
        for (int n = 0; n < 8; n++) {
            float s = nacc[n];
            s += __shfl_xor(s, 16);
            s += __shfl_xor(s, 32);
            s -= inv * fmaxf(bn[n], NEG_SLOPE * bn[n]);
            nacc[n] = s;
            s1 += s; s2 += s * s;
        }
        #pragma unroll
        for (int off = 1; off <= 8; off <<= 1) {
            s1 += __shfl_xor(s1, off);
            s2 += __shfl_xor(s2, off);
        }
        const float mu  = s1 * (1.0f / 128.0f);
        const float var = s2 * (1.0f / 128.0f) - mu * mu;
        const float rs  = rsqrtf(var + LN_EPS);

        float o0 = (nacc[n0] - mu) * rs * lw0 + lb0;
        float o1 = (nacc[n1] - mu) * rs * lw1 + lb1;
        float* rp = outp + ((size_t)d << 7);
        rp[col0] = fmaxf(o0, 0.f);
        rp[col1] = fmaxf(o1, 0.f);

        if (!hasB) break;
        // 5. rotate B -> A (static named copies; gB completed during A's compute)
        #pragma unroll
        for (int kt = 0; kt < 4; kt++) { gA[kt] = gB[kt]; rA[kt] = rB[kt]; }
        stA = stB; lenA = lenB;
        d = d2; d2 = d3; hasB = hasC; stB = stC; enB = enC; idxB = idxC;
    }
}

// ---------------- launch ----------------

extern "C" void kernel_launch(void* const* d_in, const int* in_sizes, int n_in,
                              void* d_out, int out_size, void* d_ws, size_t ws_size,
                              hipStream_t stream) {
    const float* x_user    = (const float*)d_in[0];
    const float* x_item    = (const float*)d_in[1];
    const float* W_ui      = (const float*)d_in[2];
    const float* b_ui      = (const float*)d_in[3];
    const float* W_iu      = (const float*)d_in[4];
    const float* b_iu      = (const float*)d_in[5];
    const float* ln_w_user = (const float*)d_in[6];
    const float* ln_b_user = (const float*)d_in[7];
    const float* ln_w_item = (const float*)d_in[8];
    const float* ln_b_item = (const float*)d_in[9];
    const int* esrc_ui = (const int*)d_in[10];
    const int* edst_ui = (const int*)d_in[11];
    const int* esrc_iu = (const int*)d_in[12];
    const int* edst_iu = (const int*)d_in[13];

    float* out = (float*)d_out;
    float* out_user = out;                          // N_USER x D
    float* out_item = out + (size_t)N_USER_C * D;   // N_ITEM x D

    // ws (ints): counts[NCPAD] | offsets[NCPAD] | totals[256] | sorted[E2+16]
    //            | zrow[256 halves] | xuh[100000*128 halves] | xih[50000*128 halves]
    int* counts  = (int*)d_ws;
    int* offsets = counts + NCPAD;
    int* totals  = offsets + NCPAD;
    int* sorted  = totals + 256;
    _Float16* zrow = (_Float16*)(sorted + E2 + 16);
    _Float16* xuh  = zrow + 256;
    _Float16* xih  = xuh + (size_t)N_USER_C * D;

    hipMemsetAsync(counts, 0, (size_t)NCPAD * sizeof(int), stream);

    prep_k<<<dim3(HIST_BLOCKS + CVT_BLOCKS), dim3(256), 0, stream>>>(
        edst_ui, edst_iu, counts, totals, x_user, x_item, xuh, xih, zrow);

    scan_full_k<<<dim3(NSCAN_BLOCKS), dim3(1024), 0, stream>>>(counts, offsets, totals);

    scatter_k<<<dim3(HIST_BLOCKS), dim3(256), 0, stream>>>(
        esrc_ui, edst_ui, esrc_iu, edst_iu, offsets, counts, sorted);

    conv2_k<<<dim3(CONV_BLOCKS), dim3(256), 0, stream>>>(
        xuh, xih, W_ui, b_ui, W_iu, b_iu,
        ln_w_user, ln_b_user, ln_w_item, ln_b_item,
        offsets, sorted, zrow, out_user, out_item);
}